// Round 1
// baseline (205.020 us; speedup 1.0000x reference)
//
#include <hip/hip_runtime.h>
#include <hip/hip_bf16.h>
#include <math.h>

// Problem: B=8, T=128, D=512. M = B*T = 1024 rows.
// Stage 1: six fp32 GEMMs  Y_g = x @ W_g^T + b_g   (g = qf,kf,vf,qt,kt,vt)
// Stage 2: fused feature-softmax + temporal outer-product softmax.

#define M_ROWS 1024
#define DIM    512

struct GemmArgs {
    const float* W[6];
    const float* b[6];
};

// ---------------------------------------------------------------------------
// GEMM: 64x64 output tile per block, 4x4 per thread, BK=64.
// LDS tiles stored K-major (transposed) with stride 68 floats so that
// inner-loop reads are ds_read_b128, 16B-aligned, conflict-free
// (a-reads broadcast across the 16-lane row group; b-reads 2-way = free).
// ---------------------------------------------------------------------------
#define BM 64
#define BN 64
#define BK 64
#define LDT 68   // padded stride (68*4 bytes, multiple of 16B)

__global__ __launch_bounds__(256) void gemm6(const float* __restrict__ x,
                                             GemmArgs ga,
                                             float* __restrict__ Y) {
    __shared__ float xs[BK][LDT];
    __shared__ float ws[BK][LDT];

    const int g  = blockIdx.z;
    const int m0 = blockIdx.x * BM;
    const int o0 = blockIdx.y * BN;
    const float* __restrict__ W = ga.W[g];

    const int tid = threadIdx.x;
    const int tx  = tid & 15;   // o direction (4 outputs)
    const int ty  = tid >> 4;   // m direction (4 outputs)

    float acc[4][4] = {};

    for (int k0 = 0; k0 < DIM; k0 += BK) {
        __syncthreads();
        // Stage x tile [m0..m0+64) x [k0..k0+64) and W tile [o0..)x[k0..),
        // both transposed into [k][m] / [k][o].
        #pragma unroll
        for (int t = 0; t < 4; ++t) {
            int idx = tid + t * 256;       // 0..1023
            int row = idx >> 4;            // 0..63
            int kc  = idx & 15;            // k-chunk (x4 floats)
            float4 v = *(const float4*)(x + (size_t)(m0 + row) * DIM + k0 + kc * 4);
            xs[kc * 4 + 0][row] = v.x;
            xs[kc * 4 + 1][row] = v.y;
            xs[kc * 4 + 2][row] = v.z;
            xs[kc * 4 + 3][row] = v.w;
            float4 w = *(const float4*)(W + (size_t)(o0 + row) * DIM + k0 + kc * 4);
            ws[kc * 4 + 0][row] = w.x;
            ws[kc * 4 + 1][row] = w.y;
            ws[kc * 4 + 2][row] = w.z;
            ws[kc * 4 + 3][row] = w.w;
        }
        __syncthreads();

        #pragma unroll
        for (int kk = 0; kk < BK; ++kk) {
            float4 a  = *(const float4*)&xs[kk][ty * 4];
            float4 bb = *(const float4*)&ws[kk][tx * 4];
            acc[0][0] += a.x * bb.x; acc[0][1] += a.x * bb.y;
            acc[0][2] += a.x * bb.z; acc[0][3] += a.x * bb.w;
            acc[1][0] += a.y * bb.x; acc[1][1] += a.y * bb.y;
            acc[1][2] += a.y * bb.z; acc[1][3] += a.y * bb.w;
            acc[2][0] += a.z * bb.x; acc[2][1] += a.z * bb.y;
            acc[2][2] += a.z * bb.z; acc[2][3] += a.z * bb.w;
            acc[3][0] += a.w * bb.x; acc[3][1] += a.w * bb.y;
            acc[3][2] += a.w * bb.z; acc[3][3] += a.w * bb.w;
        }
    }

    const float* __restrict__ bias = ga.b[g];
    float4 bv = *(const float4*)(bias + o0 + tx * 4);
    float* __restrict__ Yg = Y + (size_t)g * M_ROWS * DIM;
    #pragma unroll
    for (int r = 0; r < 4; ++r) {
        int row = m0 + ty * 4 + r;
        float4 ov;
        ov.x = acc[r][0] + bv.x;
        ov.y = acc[r][1] + bv.y;
        ov.z = acc[r][2] + bv.z;
        ov.w = acc[r][3] + bv.w;
        *(float4*)(Yg + (size_t)row * DIM + o0 + tx * 4) = ov;
    }
}

// ---------------------------------------------------------------------------
// Fused branches. One block of 128 threads per (b,t) row; each thread owns
// 4 feature indices i = tid + {0,128,256,384}.
//
// Feature: ctx_f[i] = exp(qf_i*kf_i)/sum_j exp(qf_j*kf_j) * vf_i
// Temporal: ctx_t[i] = sum_j exp(qt_i*kt_j) vt_j / sum_j exp(qt_i*kt_j)
//   (exp args bounded ~|3*3|=9, no max-subtraction needed in fp32)
// ---------------------------------------------------------------------------
__global__ __launch_bounds__(128) void fused_attn(const float* __restrict__ Y,
                                                  float* __restrict__ out) {
    const int row = blockIdx.x;         // 0..1023
    const int tid = threadIdx.x;        // 0..127
    const size_t S = (size_t)M_ROWS * DIM;
    const float* __restrict__ Qf = Y + 0 * S;
    const float* __restrict__ Kf = Y + 1 * S;
    const float* __restrict__ Vf = Y + 2 * S;
    const float* __restrict__ Qt = Y + 3 * S;
    const float* __restrict__ Kt = Y + 4 * S;
    const float* __restrict__ Vt = Y + 5 * S;
    const size_t base = (size_t)row * DIM;

    __shared__ float sK[DIM];
    __shared__ float sV[DIM];
    __shared__ float sred[2];

    const float LOG2E = 1.4426950408889634f;

    float ef[4], vf[4], q2[4];
    float psum = 0.f;
    #pragma unroll
    for (int w = 0; w < 4; ++w) {
        int i = tid + w * 128;
        float qf = Qf[base + i];
        float kf = Kf[base + i];
        ef[w] = __expf(qf * kf);
        psum += ef[w];
        vf[w] = Vf[base + i];
        q2[w] = Qt[base + i] * LOG2E;
        sK[i] = Kt[base + i];
        sV[i] = Vt[base + i];
    }

    // block-wide sum of psum (128 threads = 2 waves)
    #pragma unroll
    for (int off = 32; off > 0; off >>= 1) psum += __shfl_xor(psum, off);
    if ((tid & 63) == 0) sred[tid >> 6] = psum;
    __syncthreads();   // also covers sK/sV staging
    const float Ssum = sred[0] + sred[1];
    const float invS = 1.0f / Ssum;

    float den[4] = {0.f, 0.f, 0.f, 0.f};
    float num[4] = {0.f, 0.f, 0.f, 0.f};

    #pragma unroll 2
    for (int j = 0; j < DIM; j += 4) {
        float4 k4 = *(const float4*)&sK[j];
        float4 v4 = *(const float4*)&sV[j];
        #pragma unroll
        for (int w = 0; w < 4; ++w) {
            float e0 = exp2f(q2[w] * k4.x);
            float e1 = exp2f(q2[w] * k4.y);
            float e2 = exp2f(q2[w] * k4.z);
            float e3 = exp2f(q2[w] * k4.w);
            den[w] += e0; num[w] = fmaf(e0, v4.x, num[w]);
            den[w] += e1; num[w] = fmaf(e1, v4.y, num[w]);
            den[w] += e2; num[w] = fmaf(e2, v4.z, num[w]);
            den[w] += e3; num[w] = fmaf(e3, v4.w, num[w]);
        }
    }

    #pragma unroll
    for (int w = 0; w < 4; ++w) {
        int i = tid + w * 128;
        out[base + i] = ef[w] * invS * vf[w] + num[w] / den[w];
    }
}

extern "C" void kernel_launch(void* const* d_in, const int* in_sizes, int n_in,
                              void* d_out, int out_size, void* d_ws, size_t ws_size,
                              hipStream_t stream) {
    const float* x = (const float*)d_in[0];
    GemmArgs ga;
    #pragma unroll
    for (int g = 0; g < 6; ++g) {
        ga.W[g] = (const float*)d_in[1 + 2 * g];
        ga.b[g] = (const float*)d_in[2 + 2 * g];
    }
    float* Y = (float*)d_ws;   // 6 * 1024 * 512 floats = 12 MB

    dim3 grid1(M_ROWS / BM, DIM / BN, 6);   // 16 x 8 x 6 = 768 blocks
    gemm6<<<grid1, 256, 0, stream>>>(x, ga, Y);

    fused_attn<<<M_ROWS, 128, 0, stream>>>(Y, (float*)d_out);
}

// Round 2
// 151.287 us; speedup vs baseline: 1.3552x; 1.3552x over previous
//
#include <hip/hip_runtime.h>
#include <hip/hip_bf16.h>
#include <math.h>

// B=8, T=128, D=512. M = 1024 rows, N = 6*512 = 3072 concatenated outputs.
// Stage 0: split fp32 -> (hi,lo) bf16 pairs for x and all 6 W's; pack bias.
// Stage 1: one bf16 MFMA GEMM, logical K' = 1536 = 3 sections:
//          C = Ah*Bh + Ah*Bl + Al*Bh  (lo*lo term ~2^-18, dropped)
// Stage 2: fused feature-softmax + temporal outer-product softmax.

#define M_ROWS 1024
#define DIMD   512
#define NCOLS  3072
#define KPHYS  1024   // [hi | lo] physical K
#define KLOG   1536   // 3 logical sections of 512

typedef __attribute__((ext_vector_type(8))) short short8;
typedef __attribute__((ext_vector_type(4))) float f32x4;

struct PtrArgs {
    const float* W[6];
    const float* b[6];
};

// ---------------------------------------------------------------------------
// Stage 0: convert/split. idx < XN: x elements; else W elements. First 3072
// threads also pack bias.
// ---------------------------------------------------------------------------
#define XN (M_ROWS * DIMD)
#define WN (NCOLS * DIMD)

__device__ __forceinline__ unsigned short bf16_rne(float v) {
    unsigned u = __float_as_uint(v);
    u = (u + 0x7FFFu + ((u >> 16) & 1u)) >> 16;
    return (unsigned short)u;
}

__global__ __launch_bounds__(256) void convert_split(const float* __restrict__ x,
                                                     PtrArgs pa,
                                                     unsigned short* __restrict__ Aph,
                                                     unsigned short* __restrict__ Bph,
                                                     float* __restrict__ biasAll) {
    int idx = blockIdx.x * 256 + threadIdx.x;
    if (idx < NCOLS) {
        int g = idx >> 9, o = idx & 511;
        biasAll[idx] = pa.b[g][o];
    }
    if (idx < XN) {
        int m = idx >> 9, k = idx & 511;
        float v = x[idx];
        unsigned short hb = bf16_rne(v);
        float hf = __uint_as_float(((unsigned)hb) << 16);
        unsigned short lb = bf16_rne(v - hf);
        Aph[(size_t)m * KPHYS + k]       = hb;
        Aph[(size_t)m * KPHYS + 512 + k] = lb;
    } else if (idx < XN + WN) {
        int j = idx - XN;
        int n = j >> 9, k = j & 511;
        int g = n >> 9, o = n & 511;
        float v = pa.W[g][(size_t)o * DIMD + k];
        unsigned short hb = bf16_rne(v);
        float hf = __uint_as_float(((unsigned)hb) << 16);
        unsigned short lb = bf16_rne(v - hf);
        Bph[(size_t)n * KPHYS + k]       = hb;
        Bph[(size_t)n * KPHYS + 512 + k] = lb;
    }
}

// ---------------------------------------------------------------------------
// Stage 1: MFMA GEMM. 128x128 tile, BK=64, 4 waves each computing 64x64 via
// 4x4 grid of 16x16x32 bf16 MFMAs. global_load_lds width 16. LDS chunk index
// XOR-swizzled with (row&7) — swizzle applied on the GLOBAL address (LDS lane
// layout is fixed by global_load_lds), so frag ds_read_b128s hit all 32 banks.
// ---------------------------------------------------------------------------
__global__ __launch_bounds__(256) void gemm_mfma(const unsigned short* __restrict__ A,
                                                 const unsigned short* __restrict__ B,
                                                 const float* __restrict__ biasAll,
                                                 float* __restrict__ Y) {
    __shared__ __align__(16) short As[128 * 64];
    __shared__ __align__(16) short Bs[128 * 64];

    const int tid  = threadIdx.x;
    const int m0   = blockIdx.y * 128;
    const int n0   = blockIdx.x * 128;
    const int lane = tid & 63;
    const int w    = tid >> 6;
    const int wm   = w & 1;
    const int wn   = w >> 1;
    const int l15  = lane & 15;
    const int quad = lane >> 4;

    f32x4 acc[4][4];
    #pragma unroll
    for (int i = 0; i < 4; ++i)
        #pragma unroll
        for (int j = 0; j < 4; ++j)
            acc[i][j] = (f32x4){0.f, 0.f, 0.f, 0.f};

    for (int k0 = 0; k0 < KLOG; k0 += 64) {
        const int sec = k0 >> 9;
        const int kA  = (k0 & 511) + (sec == 2 ? 512 : 0);   // A: hi,hi,lo
        const int kB  = (k0 & 511) + (sec == 1 ? 512 : 0);   // B: hi,lo,hi
        __syncthreads();
        #pragma unroll
        for (int i = 0; i < 4; ++i) {
            int idx = i * 256 + tid;          // 0..1023
            int r   = idx >> 3;               // tile row 0..127
            int c   = idx & 7;                // lds chunk slot
            int cc  = c ^ (r & 7);            // global chunk (swizzle)
            const unsigned short* ga = A + (size_t)(m0 + r) * KPHYS + kA + cc * 8;
            const unsigned short* gb = B + (size_t)(n0 + r) * KPHYS + kB + cc * 8;
            __builtin_amdgcn_global_load_lds(
                (const __attribute__((address_space(1))) unsigned int*)ga,
                (__attribute__((address_space(3))) unsigned int*)&As[idx * 8], 16, 0, 0);
            __builtin_amdgcn_global_load_lds(
                (const __attribute__((address_space(1))) unsigned int*)gb,
                (__attribute__((address_space(3))) unsigned int*)&Bs[idx * 8], 16, 0, 0);
        }
        __syncthreads();

        #pragma unroll
        for (int kk = 0; kk < 2; ++kk) {
            short8 af[4], bf[4];
            const int chunk = (kk * 4 + quad) ^ (l15 & 7);
            #pragma unroll
            for (int t = 0; t < 4; ++t) {
                int ra = wm * 64 + t * 16 + l15;
                af[t] = *(const short8*)&As[ra * 64 + chunk * 8];
                int rb = wn * 64 + t * 16 + l15;
                bf[t] = *(const short8*)&Bs[rb * 64 + chunk * 8];
            }
            #pragma unroll
            for (int mt = 0; mt < 4; ++mt)
                #pragma unroll
                for (int nt = 0; nt < 4; ++nt)
                    acc[mt][nt] = __builtin_amdgcn_mfma_f32_16x16x32_bf16(
                        af[mt], bf[nt], acc[mt][nt], 0, 0, 0);
        }
    }

    // Epilogue. C/D: col = lane&15, row = quad*4 + reg  [m89-verified]
    #pragma unroll
    for (int nt = 0; nt < 4; ++nt) {
        int col = n0 + wn * 64 + nt * 16 + l15;
        float bv = biasAll[col];
        #pragma unroll
        for (int mt = 0; mt < 4; ++mt) {
            int row0 = m0 + wm * 64 + mt * 16 + quad * 4;
            #pragma unroll
            for (int r = 0; r < 4; ++r)
                Y[(size_t)(row0 + r) * NCOLS + col] = acc[mt][nt][r] + bv;
        }
    }
}

// ---------------------------------------------------------------------------
// Stage 2: fused branches. One block of 256 threads per (b,t) row; each
// thread owns i = 2*tid, 2*tid+1. Kt staged in LDS pre-scaled by log2(e);
// exp via native v_exp_f32. 8 independent accumulators for ILP.
// ---------------------------------------------------------------------------
__global__ __launch_bounds__(256) void fused_attn(const float* __restrict__ Y,
                                                  float* __restrict__ out) {
    const int row = blockIdx.x;
    const int tid = threadIdx.x;
    const float* __restrict__ Yr = Y + (size_t)row * NCOLS;

    __shared__ float sK[DIMD];
    __shared__ float sV[DIMD];
    __shared__ float sred[4];

    const float LOG2E = 1.4426950408889634f;
    const int i0 = tid * 2;

    float2 qf = *(const float2*)(Yr + i0);
    float2 kf = *(const float2*)(Yr + 512 + i0);
    float2 vf = *(const float2*)(Yr + 1024 + i0);
    float2 qt = *(const float2*)(Yr + 1536 + i0);
    float2 kt = *(const float2*)(Yr + 2048 + i0);
    float2 vt = *(const float2*)(Yr + 2560 + i0);

    float ef0 = __expf(qf.x * kf.x);
    float ef1 = __expf(qf.y * kf.y);
    sK[i0]     = kt.x * LOG2E;
    sK[i0 + 1] = kt.y * LOG2E;
    sV[i0]     = vt.x;
    sV[i0 + 1] = vt.y;

    float psum = ef0 + ef1;
    #pragma unroll
    for (int off = 32; off; off >>= 1) psum += __shfl_xor(psum, off);
    if ((tid & 63) == 0) sred[tid >> 6] = psum;
    __syncthreads();   // also covers sK/sV staging
    const float invS = 1.0f / (sred[0] + sred[1] + sred[2] + sred[3]);

    float d00 = 0.f, d01 = 0.f, d10 = 0.f, d11 = 0.f;
    float n00 = 0.f, n01 = 0.f, n10 = 0.f, n11 = 0.f;
    const float q0 = qt.x, q1 = qt.y;

    #pragma unroll 2
    for (int j = 0; j < DIMD; j += 4) {
        float4 k4 = *(const float4*)&sK[j];
        float4 v4 = *(const float4*)&sV[j];
        float e;
        e = __builtin_amdgcn_exp2f(q0 * k4.x); d00 += e; n00 = fmaf(e, v4.x, n00);
        e = __builtin_amdgcn_exp2f(q0 * k4.y); d01 += e; n01 = fmaf(e, v4.y, n01);
        e = __builtin_amdgcn_exp2f(q0 * k4.z); d00 += e; n00 = fmaf(e, v4.z, n00);
        e = __builtin_amdgcn_exp2f(q0 * k4.w); d01 += e; n01 = fmaf(e, v4.w, n01);
        e = __builtin_amdgcn_exp2f(q1 * k4.x); d10 += e; n10 = fmaf(e, v4.x, n10);
        e = __builtin_amdgcn_exp2f(q1 * k4.y); d11 += e; n11 = fmaf(e, v4.y, n11);
        e = __builtin_amdgcn_exp2f(q1 * k4.z); d10 += e; n10 = fmaf(e, v4.z, n10);
        e = __builtin_amdgcn_exp2f(q1 * k4.w); d11 += e; n11 = fmaf(e, v4.w, n11);
    }

    float2 o2;
    o2.x = ef0 * invS * vf.x + (n00 + n01) / (d00 + d01);
    o2.y = ef1 * invS * vf.y + (n10 + n11) / (d10 + d11);
    *(float2*)(out + (size_t)row * DIMD + i0) = o2;
}

extern "C" void kernel_launch(void* const* d_in, const int* in_sizes, int n_in,
                              void* d_out, int out_size, void* d_ws, size_t ws_size,
                              hipStream_t stream) {
    const float* x = (const float*)d_in[0];
    PtrArgs pa;
    for (int g = 0; g < 6; ++g) {
        pa.W[g] = (const float*)d_in[1 + 2 * g];
        pa.b[g] = (const float*)d_in[2 + 2 * g];
    }

    // Workspace layout (all 256B-aligned):
    //   Y:    [1024][3072] fp32  = 12,582,912 B
    //   Aph:  [1024][1024] bf16  =  2,097,152 B
    //   Bph:  [3072][1024] bf16  =  6,291,456 B
    //   bias: [3072] fp32        =     12,288 B    total ~20.98 MB
    char* ws = (char*)d_ws;
    float*          Y    = (float*)ws;
    unsigned short* Aph  = (unsigned short*)(ws + 12582912);
    unsigned short* Bph  = (unsigned short*)(ws + 12582912 + 2097152);
    float*          bias = (float*)(ws + 12582912 + 2097152 + 6291456);

    convert_split<<<(XN + WN) / 256, 256, 0, stream>>>(x, pa, Aph, Bph, bias);

    dim3 g1(NCOLS / 128, M_ROWS / 128);   // 24 x 8 = 192 blocks
    gemm_mfma<<<g1, 256, 0, stream>>>(Aph, Bph, bias, Y);

    fused_attn<<<M_ROWS, 256, 0, stream>>>(Y, (float*)d_out);
}

// Round 3
// 144.271 us; speedup vs baseline: 1.4211x; 1.0486x over previous
//
#include <hip/hip_runtime.h>
#include <hip/hip_bf16.h>
#include <math.h>

// B=8, T=128, D=512. M = 1024 rows, N = 6*512 = 3072 concatenated outputs.
// Stage 0: split fp32 -> (hi,lo) bf16, packed per 32-K super-chunk
//          [32 hi | 32 lo] so hi and lo stage together (frag sharing).
// Stage 1: bf16 MFMA GEMM, C = Ah*Bh + Ah*Bl + Al*Bh (lo*lo dropped).
//          64x128 tile, 4 waves (wave tile 32x64), 12 LDS reads : 24 MFMAs
//          per kk via hi/lo fragment sharing. Grid 384 blocks.
// Stage 2: fused feature-softmax + temporal outer-product softmax,
//          128 thr/row, 4 i per thread (halves LDS issue vs R2).

#define M_ROWS 1024
#define DIMD   512
#define NCOLS  3072
#define KPHYS  1024   // shorts per packed row: 16 super-chunks of [32 hi|32 lo]

typedef __attribute__((ext_vector_type(8))) short short8;
typedef __attribute__((ext_vector_type(4))) float f32x4;

struct PtrArgs {
    const float* W[6];
    const float* b[6];
};

#define XN (M_ROWS * DIMD)
#define WN (NCOLS * DIMD)

__device__ __forceinline__ unsigned short bf16_rne(float v) {
    unsigned u = __float_as_uint(v);
    u = (u + 0x7FFFu + ((u >> 16) & 1u)) >> 16;
    return (unsigned short)u;
}

// ---------------------------------------------------------------------------
// Stage 0: convert/split with interleaved hi/lo packing.
// row layout (1024 shorts): super-chunk s = k>>5 at [s*64 .. s*64+63]:
//   hi of k at s*64 + (k&31), lo at s*64 + 32 + (k&31).
// ---------------------------------------------------------------------------
__global__ __launch_bounds__(256) void convert_split(const float* __restrict__ x,
                                                     PtrArgs pa,
                                                     unsigned short* __restrict__ Aph,
                                                     unsigned short* __restrict__ Bph,
                                                     float* __restrict__ biasAll) {
    int idx = blockIdx.x * 256 + threadIdx.x;
    if (idx < NCOLS) {
        biasAll[idx] = pa.b[idx >> 9][idx & 511];
    }
    if (idx < XN) {
        int m = idx >> 9, k = idx & 511;
        int s = k >> 5, p = k & 31;
        float v = x[idx];
        unsigned short hb = bf16_rne(v);
        float hf = __uint_as_float(((unsigned)hb) << 16);
        unsigned short lb = bf16_rne(v - hf);
        Aph[(size_t)m * KPHYS + s * 64 + p]      = hb;
        Aph[(size_t)m * KPHYS + s * 64 + 32 + p] = lb;
    } else if (idx < XN + WN) {
        int j = idx - XN;
        int n = j >> 9, k = j & 511;
        int g = n >> 9, o = n & 511;
        int s = k >> 5, p = k & 31;
        float v = pa.W[g][(size_t)o * DIMD + k];
        unsigned short hb = bf16_rne(v);
        float hf = __uint_as_float(((unsigned)hb) << 16);
        unsigned short lb = bf16_rne(v - hf);
        Bph[(size_t)n * KPHYS + s * 64 + p]      = hb;
        Bph[(size_t)n * KPHYS + s * 64 + 32 + p] = lb;
    }
}

// ---------------------------------------------------------------------------
// Stage 1: MFMA GEMM. Block tile 64(M) x 128(N), 4 waves as 2(M-half)x2(N-half),
// wave tile 32x64 = 2x4 of 16x16x32 MFMAs, x3 for hi/lo terms.
// Per iter: stage 128 phys shorts/row (= 64 logical K, hi+lo) -> 48 KB LDS.
// 16B chunk index XOR-swizzled with (row&15); swizzle applied on the GLOBAL
// address (global_load_lds pins LDS lane layout), so frag ds_read_b128s are
// conflict-free.
// ---------------------------------------------------------------------------
__global__ __launch_bounds__(256) void gemm_mfma(const unsigned short* __restrict__ A,
                                                 const unsigned short* __restrict__ B,
                                                 const float* __restrict__ biasAll,
                                                 float* __restrict__ Y) {
    __shared__ __align__(16) short As[64 * 128];    // 16 KB
    __shared__ __align__(16) short Bs[128 * 128];   // 32 KB

    const int tid  = threadIdx.x;
    const int m0   = blockIdx.y * 64;
    const int n0   = blockIdx.x * 128;
    const int lane = tid & 63;
    const int w    = tid >> 6;
    const int wm   = w & 1;      // M half (32 rows)
    const int wn   = w >> 1;     // N half (64 cols)
    const int l15  = lane & 15;
    const int quad = lane >> 4;

    f32x4 acc[2][4];
    #pragma unroll
    for (int i = 0; i < 2; ++i)
        #pragma unroll
        for (int j = 0; j < 4; ++j)
            acc[i][j] = (f32x4){0.f, 0.f, 0.f, 0.f};

    for (int it = 0; it < 8; ++it) {
        const int kbase = it * 128;
        __syncthreads();
        // stage A: 64 rows x 16 chunks = 1024 chunk-loads
        #pragma unroll
        for (int t = 0; t < 4; ++t) {
            int idx = t * 256 + tid;
            int r = idx >> 4, c = idx & 15;
            int cc = c ^ (r & 15);
            const unsigned short* ga = A + (size_t)(m0 + r) * KPHYS + kbase + cc * 8;
            __builtin_amdgcn_global_load_lds(
                (const __attribute__((address_space(1))) unsigned int*)ga,
                (__attribute__((address_space(3))) unsigned int*)&As[idx * 8], 16, 0, 0);
        }
        // stage B: 128 rows x 16 chunks = 2048 chunk-loads
        #pragma unroll
        for (int t = 0; t < 8; ++t) {
            int idx = t * 256 + tid;
            int r = idx >> 4, c = idx & 15;
            int cc = c ^ (r & 15);
            const unsigned short* gb = B + (size_t)(n0 + r) * KPHYS + kbase + cc * 8;
            __builtin_amdgcn_global_load_lds(
                (const __attribute__((address_space(1))) unsigned int*)gb,
                (__attribute__((address_space(3))) unsigned int*)&Bs[idx * 8], 16, 0, 0);
        }
        __syncthreads();

        #pragma unroll
        for (int kk = 0; kk < 2; ++kk) {
            short8 ah[2], al[2], bh[4], bl[4];
            #pragma unroll
            for (int mt = 0; mt < 2; ++mt) {
                int rA = wm * 32 + mt * 16 + l15;
                int ch = (kk * 8 + quad)     ^ (rA & 15);
                int cl = (kk * 8 + 4 + quad) ^ (rA & 15);
                ah[mt] = *(const short8*)&As[(rA * 16 + ch) * 8];
                al[mt] = *(const short8*)&As[(rA * 16 + cl) * 8];
            }
            #pragma unroll
            for (int nt = 0; nt < 4; ++nt) {
                int rB = wn * 64 + nt * 16 + l15;
                int ch = (kk * 8 + quad)     ^ (rB & 15);
                int cl = (kk * 8 + 4 + quad) ^ (rB & 15);
                bh[nt] = *(const short8*)&Bs[(rB * 16 + ch) * 8];
                bl[nt] = *(const short8*)&Bs[(rB * 16 + cl) * 8];
            }
            #pragma unroll
            for (int mt = 0; mt < 2; ++mt)
                #pragma unroll
                for (int nt = 0; nt < 4; ++nt) {
                    acc[mt][nt] = __builtin_amdgcn_mfma_f32_16x16x32_bf16(
                        ah[mt], bh[nt], acc[mt][nt], 0, 0, 0);
                    acc[mt][nt] = __builtin_amdgcn_mfma_f32_16x16x32_bf16(
                        ah[mt], bl[nt], acc[mt][nt], 0, 0, 0);
                    acc[mt][nt] = __builtin_amdgcn_mfma_f32_16x16x32_bf16(
                        al[mt], bh[nt], acc[mt][nt], 0, 0, 0);
                }
        }
    }

    // Epilogue. C/D: col = lane&15, row = quad*4 + reg  [m89-verified]
    #pragma unroll
    for (int nt = 0; nt < 4; ++nt) {
        int col = n0 + wn * 64 + nt * 16 + l15;
        float bv = biasAll[col];
        #pragma unroll
        for (int mt = 0; mt < 2; ++mt) {
            int row0 = m0 + wm * 32 + mt * 16 + quad * 4;
            #pragma unroll
            for (int r = 0; r < 4; ++r)
                Y[(size_t)(row0 + r) * NCOLS + col] = acc[mt][nt][r] + bv;
        }
    }
}

// ---------------------------------------------------------------------------
// Stage 2: fused branches. 128 threads per (b,t) row; each thread owns
// i = tid + {0,128,256,384}. One sK/sV float4 pair feeds 16 exp-elements.
// Kt pre-scaled by log2(e) in LDS; raw v_exp_f32 via builtin.
// ---------------------------------------------------------------------------
__global__ __launch_bounds__(128) void fused_attn(const float* __restrict__ Y,
                                                  float* __restrict__ out) {
    const int row = blockIdx.x;
    const int tid = threadIdx.x;
    const float* __restrict__ Yr = Y + (size_t)row * NCOLS;

    __shared__ float sK[DIMD];
    __shared__ float sV[DIMD];
    __shared__ float sred[2];

    const float LOG2E = 1.4426950408889634f;

    float ef[4], vf[4], q[4];
    float psum = 0.f;
    #pragma unroll
    for (int w = 0; w < 4; ++w) {
        int i = tid + w * 128;
        float qf = Yr[i];
        float kf = Yr[512 + i];
        ef[w] = __builtin_amdgcn_exp2f(qf * kf * LOG2E);
        psum += ef[w];
        vf[w] = Yr[1024 + i];
        q[w]  = Yr[1536 + i];
        sK[i] = Yr[2048 + i] * LOG2E;
        sV[i] = Yr[2560 + i];
    }

    #pragma unroll
    for (int off = 32; off; off >>= 1) psum += __shfl_xor(psum, off);
    if ((tid & 63) == 0) sred[tid >> 6] = psum;
    __syncthreads();   // also covers sK/sV staging
    const float invS = 1.0f / (sred[0] + sred[1]);

    float den[4] = {0.f, 0.f, 0.f, 0.f};
    float num[4] = {0.f, 0.f, 0.f, 0.f};

    #pragma unroll 2
    for (int j = 0; j < DIMD; j += 4) {
        float4 k4 = *(const float4*)&sK[j];
        float4 v4 = *(const float4*)&sV[j];
        #pragma unroll
        for (int w = 0; w < 4; ++w) {
            float e0 = __builtin_amdgcn_exp2f(q[w] * k4.x);
            float e1 = __builtin_amdgcn_exp2f(q[w] * k4.y);
            float e2 = __builtin_amdgcn_exp2f(q[w] * k4.z);
            float e3 = __builtin_amdgcn_exp2f(q[w] * k4.w);
            den[w] += e0; num[w] = fmaf(e0, v4.x, num[w]);
            den[w] += e1; num[w] = fmaf(e1, v4.y, num[w]);
            den[w] += e2; num[w] = fmaf(e2, v4.z, num[w]);
            den[w] += e3; num[w] = fmaf(e3, v4.w, num[w]);
        }
    }

    #pragma unroll
    for (int w = 0; w < 4; ++w) {
        int i = tid + w * 128;
        out[(size_t)row * DIMD + i] = ef[w] * invS * vf[w] + num[w] / den[w];
    }
}

extern "C" void kernel_launch(void* const* d_in, const int* in_sizes, int n_in,
                              void* d_out, int out_size, void* d_ws, size_t ws_size,
                              hipStream_t stream) {
    const float* x = (const float*)d_in[0];
    PtrArgs pa;
    for (int g = 0; g < 6; ++g) {
        pa.W[g] = (const float*)d_in[1 + 2 * g];
        pa.b[g] = (const float*)d_in[2 + 2 * g];
    }

    // Workspace layout:
    //   Y:    [1024][3072] fp32  = 12,582,912 B
    //   Aph:  [1024][1024] bf16  =  2,097,152 B
    //   Bph:  [3072][1024] bf16  =  6,291,456 B
    //   bias: [3072] fp32        =     12,288 B
    char* ws = (char*)d_ws;
    float*          Y    = (float*)ws;
    unsigned short* Aph  = (unsigned short*)(ws + 12582912);
    unsigned short* Bph  = (unsigned short*)(ws + 12582912 + 2097152);
    float*          bias = (float*)(ws + 12582912 + 2097152 + 6291456);

    convert_split<<<(XN + WN) / 256, 256, 0, stream>>>(x, pa, Aph, Bph, bias);

    dim3 g1(NCOLS / 128, M_ROWS / 64);   // 24 x 16 = 384 blocks
    gemm_mfma<<<g1, 256, 0, stream>>>(Aph, Bph, bias, Y);

    fused_attn<<<M_ROWS, 128, 0, stream>>>(Y, (float*)d_out);
}

// Round 4
// 133.820 us; speedup vs baseline: 1.5321x; 1.0781x over previous
//
#include <hip/hip_runtime.h>
#include <hip/hip_bf16.h>
#include <math.h>

// B=8, T=128, D=512. M = 1024 rows, N = 6*512 = 3072 concatenated outputs.
// Stage 0: split fp32 -> (hi,lo) bf16, packed per 32-K super-chunk
//          [32 hi | 32 lo] so hi and lo stage together (frag sharing).
// Stage 1: bf16 MFMA GEMM, C = Ah*Bh + Ah*Bl + Al*Bh (lo*lo dropped).
//          64x128 tile, 4 waves (wave tile 32x64), 12 LDS reads : 24 MFMAs
//          per kk via hi/lo fragment sharing. Grid 384 blocks.
// Stage 2: fused softmax branches. 512 thr/block, 1 i/thread — 8192 waves
//          (4x oversubscription) so the exp(trans) pipe is latency-hidden
//          by TLP. R3's 128-thr version stalled at 11% occupancy.

#define M_ROWS 1024
#define DIMD   512
#define NCOLS  3072
#define KPHYS  1024   // shorts per packed row: 16 super-chunks of [32 hi|32 lo]

typedef __attribute__((ext_vector_type(8))) short short8;
typedef __attribute__((ext_vector_type(4))) float f32x4;

struct PtrArgs {
    const float* W[6];
    const float* b[6];
};

#define XN (M_ROWS * DIMD)
#define WN (NCOLS * DIMD)

__device__ __forceinline__ unsigned short bf16_rne(float v) {
    unsigned u = __float_as_uint(v);
    u = (u + 0x7FFFu + ((u >> 16) & 1u)) >> 16;
    return (unsigned short)u;
}

// ---------------------------------------------------------------------------
// Stage 0: convert/split with interleaved hi/lo packing.
// row layout (1024 shorts): super-chunk s = k>>5 at [s*64 .. s*64+63]:
//   hi of k at s*64 + (k&31), lo at s*64 + 32 + (k&31).
// ---------------------------------------------------------------------------
__global__ __launch_bounds__(256) void convert_split(const float* __restrict__ x,
                                                     PtrArgs pa,
                                                     unsigned short* __restrict__ Aph,
                                                     unsigned short* __restrict__ Bph,
                                                     float* __restrict__ biasAll) {
    int idx = blockIdx.x * 256 + threadIdx.x;
    if (idx < NCOLS) {
        biasAll[idx] = pa.b[idx >> 9][idx & 511];
    }
    if (idx < XN) {
        int m = idx >> 9, k = idx & 511;
        int s = k >> 5, p = k & 31;
        float v = x[idx];
        unsigned short hb = bf16_rne(v);
        float hf = __uint_as_float(((unsigned)hb) << 16);
        unsigned short lb = bf16_rne(v - hf);
        Aph[(size_t)m * KPHYS + s * 64 + p]      = hb;
        Aph[(size_t)m * KPHYS + s * 64 + 32 + p] = lb;
    } else if (idx < XN + WN) {
        int j = idx - XN;
        int n = j >> 9, k = j & 511;
        int g = n >> 9, o = n & 511;
        int s = k >> 5, p = k & 31;
        float v = pa.W[g][(size_t)o * DIMD + k];
        unsigned short hb = bf16_rne(v);
        float hf = __uint_as_float(((unsigned)hb) << 16);
        unsigned short lb = bf16_rne(v - hf);
        Bph[(size_t)n * KPHYS + s * 64 + p]      = hb;
        Bph[(size_t)n * KPHYS + s * 64 + 32 + p] = lb;
    }
}

// ---------------------------------------------------------------------------
// Stage 1: MFMA GEMM. Block tile 64(M) x 128(N), 4 waves as 2(M-half)x2(N-half),
// wave tile 32x64 = 2x4 of 16x16x32 MFMAs, x3 for hi/lo terms.
// Per iter: stage 128 phys shorts/row (= 64 logical K, hi+lo) -> 48 KB LDS.
// 16B chunk index XOR-swizzled with (row&15); swizzle applied on the GLOBAL
// address (global_load_lds pins LDS lane layout), so frag ds_read_b128s are
// conflict-free.
// ---------------------------------------------------------------------------
__global__ __launch_bounds__(256) void gemm_mfma(const unsigned short* __restrict__ A,
                                                 const unsigned short* __restrict__ B,
                                                 const float* __restrict__ biasAll,
                                                 float* __restrict__ Y) {
    __shared__ __align__(16) short As[64 * 128];    // 16 KB
    __shared__ __align__(16) short Bs[128 * 128];   // 32 KB

    const int tid  = threadIdx.x;
    const int m0   = blockIdx.y * 64;
    const int n0   = blockIdx.x * 128;
    const int lane = tid & 63;
    const int w    = tid >> 6;
    const int wm   = w & 1;      // M half (32 rows)
    const int wn   = w >> 1;     // N half (64 cols)
    const int l15  = lane & 15;
    const int quad = lane >> 4;

    f32x4 acc[2][4];
    #pragma unroll
    for (int i = 0; i < 2; ++i)
        #pragma unroll
        for (int j = 0; j < 4; ++j)
            acc[i][j] = (f32x4){0.f, 0.f, 0.f, 0.f};

    for (int it = 0; it < 8; ++it) {
        const int kbase = it * 128;
        __syncthreads();
        // stage A: 64 rows x 16 chunks = 1024 chunk-loads
        #pragma unroll
        for (int t = 0; t < 4; ++t) {
            int idx = t * 256 + tid;
            int r = idx >> 4, c = idx & 15;
            int cc = c ^ (r & 15);
            const unsigned short* ga = A + (size_t)(m0 + r) * KPHYS + kbase + cc * 8;
            __builtin_amdgcn_global_load_lds(
                (const __attribute__((address_space(1))) unsigned int*)ga,
                (__attribute__((address_space(3))) unsigned int*)&As[idx * 8], 16, 0, 0);
        }
        // stage B: 128 rows x 16 chunks = 2048 chunk-loads
        #pragma unroll
        for (int t = 0; t < 8; ++t) {
            int idx = t * 256 + tid;
            int r = idx >> 4, c = idx & 15;
            int cc = c ^ (r & 15);
            const unsigned short* gb = B + (size_t)(n0 + r) * KPHYS + kbase + cc * 8;
            __builtin_amdgcn_global_load_lds(
                (const __attribute__((address_space(1))) unsigned int*)gb,
                (__attribute__((address_space(3))) unsigned int*)&Bs[idx * 8], 16, 0, 0);
        }
        __syncthreads();

        #pragma unroll
        for (int kk = 0; kk < 2; ++kk) {
            short8 ah[2], al[2], bh[4], bl[4];
            #pragma unroll
            for (int mt = 0; mt < 2; ++mt) {
                int rA = wm * 32 + mt * 16 + l15;
                int ch = (kk * 8 + quad)     ^ (rA & 15);
                int cl = (kk * 8 + 4 + quad) ^ (rA & 15);
                ah[mt] = *(const short8*)&As[(rA * 16 + ch) * 8];
                al[mt] = *(const short8*)&As[(rA * 16 + cl) * 8];
            }
            #pragma unroll
            for (int nt = 0; nt < 4; ++nt) {
                int rB = wn * 64 + nt * 16 + l15;
                int ch = (kk * 8 + quad)     ^ (rB & 15);
                int cl = (kk * 8 + 4 + quad) ^ (rB & 15);
                bh[nt] = *(const short8*)&Bs[(rB * 16 + ch) * 8];
                bl[nt] = *(const short8*)&Bs[(rB * 16 + cl) * 8];
            }
            #pragma unroll
            for (int mt = 0; mt < 2; ++mt)
                #pragma unroll
                for (int nt = 0; nt < 4; ++nt) {
                    acc[mt][nt] = __builtin_amdgcn_mfma_f32_16x16x32_bf16(
                        ah[mt], bh[nt], acc[mt][nt], 0, 0, 0);
                    acc[mt][nt] = __builtin_amdgcn_mfma_f32_16x16x32_bf16(
                        ah[mt], bl[nt], acc[mt][nt], 0, 0, 0);
                    acc[mt][nt] = __builtin_amdgcn_mfma_f32_16x16x32_bf16(
                        al[mt], bh[nt], acc[mt][nt], 0, 0, 0);
                }
        }
    }

    // Epilogue. C/D: col = lane&15, row = quad*4 + reg  [m89-verified]
    #pragma unroll
    for (int nt = 0; nt < 4; ++nt) {
        int col = n0 + wn * 64 + nt * 16 + l15;
        float bv = biasAll[col];
        #pragma unroll
        for (int mt = 0; mt < 2; ++mt) {
            int row0 = m0 + wm * 32 + mt * 16 + quad * 4;
            #pragma unroll
            for (int r = 0; r < 4; ++r)
                Y[(size_t)(row0 + r) * NCOLS + col] = acc[mt][nt][r] + bv;
        }
    }
}

// ---------------------------------------------------------------------------
// Stage 2: fused branches. 512 threads per (b,t) row; each thread owns ONE
// feature index i = tid. 8 waves/block, 1024 blocks -> 8192 waves (4x
// oversubscription) so v_exp_f32 (trans pipe) latency is hidden by TLP.
// sK holds Kt*log2(e); sK/sV reads are wave-broadcast (conflict-free).
// ---------------------------------------------------------------------------
__global__ __launch_bounds__(512) void fused_attn(const float* __restrict__ Y,
                                                  float* __restrict__ out) {
    const int row = blockIdx.x;
    const int tid = threadIdx.x;
    const float* __restrict__ Yr = Y + (size_t)row * NCOLS;

    __shared__ float sK[DIMD];
    __shared__ float sV[DIMD];
    __shared__ float sred[8];

    const float LOG2E = 1.4426950408889634f;

    float qf = Yr[tid];
    float kf = Yr[512 + tid];
    float vf = Yr[1024 + tid];
    float q  = Yr[1536 + tid];
    sK[tid]  = Yr[2048 + tid] * LOG2E;
    sV[tid]  = Yr[2560 + tid];

    float ef = __builtin_amdgcn_exp2f(qf * kf * LOG2E);
    float psum = ef;
    #pragma unroll
    for (int off = 32; off; off >>= 1) psum += __shfl_xor(psum, off);
    if ((tid & 63) == 0) sred[tid >> 6] = psum;
    __syncthreads();   // also covers sK/sV staging
    float Ssum = 0.f;
    #pragma unroll
    for (int wv = 0; wv < 8; ++wv) Ssum += sred[wv];
    const float invS = 1.0f / Ssum;

    float d0 = 0.f, d1 = 0.f, d2 = 0.f, d3 = 0.f;
    float n0 = 0.f, n1 = 0.f, n2 = 0.f, n3 = 0.f;

    #pragma unroll 2
    for (int j = 0; j < DIMD; j += 4) {
        float4 k4 = *(const float4*)&sK[j];
        float4 v4 = *(const float4*)&sV[j];
        float e0 = __builtin_amdgcn_exp2f(q * k4.x);
        float e1 = __builtin_amdgcn_exp2f(q * k4.y);
        float e2 = __builtin_amdgcn_exp2f(q * k4.z);
        float e3 = __builtin_amdgcn_exp2f(q * k4.w);
        d0 += e0; n0 = fmaf(e0, v4.x, n0);
        d1 += e1; n1 = fmaf(e1, v4.y, n1);
        d2 += e2; n2 = fmaf(e2, v4.z, n2);
        d3 += e3; n3 = fmaf(e3, v4.w, n3);
    }

    out[(size_t)row * DIMD + tid] =
        ef * invS * vf + ((n0 + n1) + (n2 + n3)) / ((d0 + d1) + (d2 + d3));
}

extern "C" void kernel_launch(void* const* d_in, const int* in_sizes, int n_in,
                              void* d_out, int out_size, void* d_ws, size_t ws_size,
                              hipStream_t stream) {
    const float* x = (const float*)d_in[0];
    PtrArgs pa;
    for (int g = 0; g < 6; ++g) {
        pa.W[g] = (const float*)d_in[1 + 2 * g];
        pa.b[g] = (const float*)d_in[2 + 2 * g];
    }

    // Workspace layout:
    //   Y:    [1024][3072] fp32  = 12,582,912 B
    //   Aph:  [1024][1024] bf16  =  2,097,152 B
    //   Bph:  [3072][1024] bf16  =  6,291,456 B
    //   bias: [3072] fp32        =     12,288 B
    char* ws = (char*)d_ws;
    float*          Y    = (float*)ws;
    unsigned short* Aph  = (unsigned short*)(ws + 12582912);
    unsigned short* Bph  = (unsigned short*)(ws + 12582912 + 2097152);
    float*          bias = (float*)(ws + 12582912 + 2097152 + 6291456);

    convert_split<<<(XN + WN) / 256, 256, 0, stream>>>(x, pa, Aph, Bph, bias);

    dim3 g1(NCOLS / 128, M_ROWS / 64);   // 24 x 16 = 384 blocks
    gemm_mfma<<<g1, 256, 0, stream>>>(Aph, Bph, bias, Y);

    fused_attn<<<M_ROWS, 512, 0, stream>>>(Y, (float*)d_out);
}

// Round 5
// 120.984 us; speedup vs baseline: 1.6946x; 1.1061x over previous
//
#include <hip/hip_runtime.h>
#include <hip/hip_bf16.h>
#include <math.h>

// B=8, T=128, D=512. M = 1024 rows, N = 6*512 = 3072 concatenated outputs.
// Stage 0: split fp32 -> (hi,lo) bf16, packed per 32-K super-chunk.
// Stage 1: bf16 MFMA GEMM, C = Ah*Bh + Ah*Bl + Al*Bh.
// Stage 2: fused branches. Temporal softmax via degree-24 Taylor moment
//          factorization: e^{qk} = sum_p (qk)^p/p!  ->  per-row moments
//          M_p = sum_j k^p v_j, N_p = sum_j k^p, then Horner in q per i.
//          Replaces 268M trans-pipe exps with ~50 fmas/element of VALU.
//          Error: trunc ~1e-3 abs / den(>=300) + Horner eps*B/G*24 ~ 1e-5.

#define M_ROWS 1024
#define DIMD   512
#define NCOLS  3072
#define KPHYS  1024

typedef __attribute__((ext_vector_type(8))) short short8;
typedef __attribute__((ext_vector_type(4))) float f32x4;

struct PtrArgs {
    const float* W[6];
    const float* b[6];
};

#define XN (M_ROWS * DIMD)
#define WN (NCOLS * DIMD)

__device__ __forceinline__ unsigned short bf16_rne(float v) {
    unsigned u = __float_as_uint(v);
    u = (u + 0x7FFFu + ((u >> 16) & 1u)) >> 16;
    return (unsigned short)u;
}

__device__ __constant__ float INVFACT[25] = {
    1.0f, 1.0f, 0.5f,
    1.6666666666666666e-01f, 4.1666666666666664e-02f, 8.3333333333333332e-03f,
    1.3888888888888889e-03f, 1.9841269841269841e-04f, 2.4801587301587302e-05f,
    2.7557319223985893e-06f, 2.7557319223985888e-07f, 2.5052108385441720e-08f,
    2.0876756987868100e-09f, 1.6059043836821613e-10f, 1.1470745597729725e-11f,
    7.6471637318198164e-13f, 4.7794773323873853e-14f, 2.8114572543455206e-15f,
    1.5619206968586225e-16f, 8.2206352466243295e-18f, 4.1103176233121648e-19f,
    1.9572941063391263e-20f, 8.8967913924505741e-22f, 3.8681701706306835e-23f,
    1.6117375710961184e-24f
};

// ---------------------------------------------------------------------------
// Stage 0: convert/split with interleaved hi/lo packing.
// ---------------------------------------------------------------------------
__global__ __launch_bounds__(256) void convert_split(const float* __restrict__ x,
                                                     PtrArgs pa,
                                                     unsigned short* __restrict__ Aph,
                                                     unsigned short* __restrict__ Bph,
                                                     float* __restrict__ biasAll) {
    int idx = blockIdx.x * 256 + threadIdx.x;
    if (idx < NCOLS) {
        biasAll[idx] = pa.b[idx >> 9][idx & 511];
    }
    if (idx < XN) {
        int m = idx >> 9, k = idx & 511;
        int s = k >> 5, p = k & 31;
        float v = x[idx];
        unsigned short hb = bf16_rne(v);
        float hf = __uint_as_float(((unsigned)hb) << 16);
        unsigned short lb = bf16_rne(v - hf);
        Aph[(size_t)m * KPHYS + s * 64 + p]      = hb;
        Aph[(size_t)m * KPHYS + s * 64 + 32 + p] = lb;
    } else if (idx < XN + WN) {
        int j = idx - XN;
        int n = j >> 9, k = j & 511;
        int g = n >> 9, o = n & 511;
        int s = k >> 5, p = k & 31;
        float v = pa.W[g][(size_t)o * DIMD + k];
        unsigned short hb = bf16_rne(v);
        float hf = __uint_as_float(((unsigned)hb) << 16);
        unsigned short lb = bf16_rne(v - hf);
        Bph[(size_t)n * KPHYS + s * 64 + p]      = hb;
        Bph[(size_t)n * KPHYS + s * 64 + 32 + p] = lb;
    }
}

// ---------------------------------------------------------------------------
// Stage 1: MFMA GEMM (unchanged from R4). 64x128 tile, hi/lo frag sharing.
// ---------------------------------------------------------------------------
__global__ __launch_bounds__(256) void gemm_mfma(const unsigned short* __restrict__ A,
                                                 const unsigned short* __restrict__ B,
                                                 const float* __restrict__ biasAll,
                                                 float* __restrict__ Y) {
    __shared__ __align__(16) short As[64 * 128];
    __shared__ __align__(16) short Bs[128 * 128];

    const int tid  = threadIdx.x;
    const int m0   = blockIdx.y * 64;
    const int n0   = blockIdx.x * 128;
    const int lane = tid & 63;
    const int w    = tid >> 6;
    const int wm   = w & 1;
    const int wn   = w >> 1;
    const int l15  = lane & 15;
    const int quad = lane >> 4;

    f32x4 acc[2][4];
    #pragma unroll
    for (int i = 0; i < 2; ++i)
        #pragma unroll
        for (int j = 0; j < 4; ++j)
            acc[i][j] = (f32x4){0.f, 0.f, 0.f, 0.f};

    for (int it = 0; it < 8; ++it) {
        const int kbase = it * 128;
        __syncthreads();
        #pragma unroll
        for (int t = 0; t < 4; ++t) {
            int idx = t * 256 + tid;
            int r = idx >> 4, c = idx & 15;
            int cc = c ^ (r & 15);
            const unsigned short* ga = A + (size_t)(m0 + r) * KPHYS + kbase + cc * 8;
            __builtin_amdgcn_global_load_lds(
                (const __attribute__((address_space(1))) unsigned int*)ga,
                (__attribute__((address_space(3))) unsigned int*)&As[idx * 8], 16, 0, 0);
        }
        #pragma unroll
        for (int t = 0; t < 8; ++t) {
            int idx = t * 256 + tid;
            int r = idx >> 4, c = idx & 15;
            int cc = c ^ (r & 15);
            const unsigned short* gb = B + (size_t)(n0 + r) * KPHYS + kbase + cc * 8;
            __builtin_amdgcn_global_load_lds(
                (const __attribute__((address_space(1))) unsigned int*)gb,
                (__attribute__((address_space(3))) unsigned int*)&Bs[idx * 8], 16, 0, 0);
        }
        __syncthreads();

        #pragma unroll
        for (int kk = 0; kk < 2; ++kk) {
            short8 ah[2], al[2], bh[4], bl[4];
            #pragma unroll
            for (int mt = 0; mt < 2; ++mt) {
                int rA = wm * 32 + mt * 16 + l15;
                int ch = (kk * 8 + quad)     ^ (rA & 15);
                int cl = (kk * 8 + 4 + quad) ^ (rA & 15);
                ah[mt] = *(const short8*)&As[(rA * 16 + ch) * 8];
                al[mt] = *(const short8*)&As[(rA * 16 + cl) * 8];
            }
            #pragma unroll
            for (int nt = 0; nt < 4; ++nt) {
                int rB = wn * 64 + nt * 16 + l15;
                int ch = (kk * 8 + quad)     ^ (rB & 15);
                int cl = (kk * 8 + 4 + quad) ^ (rB & 15);
                bh[nt] = *(const short8*)&Bs[(rB * 16 + ch) * 8];
                bl[nt] = *(const short8*)&Bs[(rB * 16 + cl) * 8];
            }
            #pragma unroll
            for (int mt = 0; mt < 2; ++mt)
                #pragma unroll
                for (int nt = 0; nt < 4; ++nt) {
                    acc[mt][nt] = __builtin_amdgcn_mfma_f32_16x16x32_bf16(
                        ah[mt], bh[nt], acc[mt][nt], 0, 0, 0);
                    acc[mt][nt] = __builtin_amdgcn_mfma_f32_16x16x32_bf16(
                        ah[mt], bl[nt], acc[mt][nt], 0, 0, 0);
                    acc[mt][nt] = __builtin_amdgcn_mfma_f32_16x16x32_bf16(
                        al[mt], bh[nt], acc[mt][nt], 0, 0, 0);
                }
        }
    }

    #pragma unroll
    for (int nt = 0; nt < 4; ++nt) {
        int col = n0 + wn * 64 + nt * 16 + l15;
        float bv = biasAll[col];
        #pragma unroll
        for (int mt = 0; mt < 2; ++mt) {
            int row0 = m0 + wm * 32 + mt * 16 + quad * 4;
            #pragma unroll
            for (int r = 0; r < 4; ++r)
                Y[(size_t)(row0 + r) * NCOLS + col] = acc[mt][nt][r] + bv;
        }
    }
}

// ---------------------------------------------------------------------------
// Stage 2: fused branches via Taylor moments. 256 threads per (b,t) row;
// each thread owns 2 j's (moments) and 2 i's (Horner + feature branch).
//   M_p = sum_j k_j^p v_j, N_p = sum_j k_j^p  (p = 0..24)
//   F(q) = sum_p (M_p/p!) q^p,  G(q) = sum_p (N_p/p!) q^p
//   ctx_t[i] = F(q_i)/G(q_i)
// ---------------------------------------------------------------------------
__global__ __launch_bounds__(256) void fused_attn(const float* __restrict__ Y,
                                                  float* __restrict__ out) {
    const int row  = blockIdx.x;
    const int tid  = threadIdx.x;
    const int lane = tid & 63;
    const int wave = tid >> 6;
    const float* __restrict__ Yr = Y + (size_t)row * NCOLS;

    __shared__ float sred[4];
    __shared__ float partM[25][4];
    __shared__ float partN[25][4];
    __shared__ float cF[25];
    __shared__ float cG[25];

    const float LOG2E = 1.4426950408889634f;

    // thread owns feature/temporal indices i0 = tid, i1 = tid + 256
    float qf0 = Yr[tid],        qf1 = Yr[tid + 256];
    float kf0 = Yr[512 + tid],  kf1 = Yr[768 + tid];
    float vf0 = Yr[1024 + tid], vf1 = Yr[1280 + tid];
    float t0  = Yr[1536 + tid], t1  = Yr[1792 + tid];
    float k0  = Yr[2048 + tid], k1  = Yr[2304 + tid];
    float v0  = Yr[2560 + tid], v1  = Yr[2816 + tid];

    // feature branch: exp + block sum
    float ef0 = __builtin_amdgcn_exp2f(qf0 * kf0 * LOG2E);
    float ef1 = __builtin_amdgcn_exp2f(qf1 * kf1 * LOG2E);
    float psum = ef0 + ef1;
    #pragma unroll
    for (int off = 32; off; off >>= 1) psum += __shfl_xor(psum, off);
    if (lane == 0) sred[wave] = psum;

    // temporal moments (thread owns j0 = tid, j1 = tid + 256)
    float kp0 = 1.f, kp1 = 1.f;
    #pragma unroll
    for (int p = 0; p < 25; ++p) {
        float mv = fmaf(kp1, v1, kp0 * v0);
        float nv = kp0 + kp1;
        #pragma unroll
        for (int off = 32; off; off >>= 1) {
            mv += __shfl_xor(mv, off);
            nv += __shfl_xor(nv, off);
        }
        if (lane == 0) { partM[p][wave] = mv; partN[p][wave] = nv; }
        kp0 *= k0; kp1 *= k1;
    }
    __syncthreads();

    if (tid < 50) {
        bool isM = tid < 25;
        int p = isM ? tid : tid - 25;
        float s = isM
            ? (partM[p][0] + partM[p][1]) + (partM[p][2] + partM[p][3])
            : (partN[p][0] + partN[p][1]) + (partN[p][2] + partN[p][3]);
        s *= INVFACT[p];
        if (isM) cF[p] = s; else cG[p] = s;
    }
    __syncthreads();

    const float invS = 1.f / ((sred[0] + sred[1]) + (sred[2] + sred[3]));

    // Horner in q for both owned i's (coefficients broadcast from LDS)
    float F0 = cF[24], G0 = cG[24];
    float F1 = F0,     G1 = G0;
    #pragma unroll
    for (int p = 23; p >= 0; --p) {
        float cf = cF[p], cg = cG[p];
        F0 = fmaf(F0, t0, cf); G0 = fmaf(G0, t0, cg);
        F1 = fmaf(F1, t1, cf); G1 = fmaf(G1, t1, cg);
    }

    out[(size_t)row * DIMD + tid]       = ef0 * invS * vf0 + F0 / G0;
    out[(size_t)row * DIMD + tid + 256] = ef1 * invS * vf1 + F1 / G1;
}

extern "C" void kernel_launch(void* const* d_in, const int* in_sizes, int n_in,
                              void* d_out, int out_size, void* d_ws, size_t ws_size,
                              hipStream_t stream) {
    const float* x = (const float*)d_in[0];
    PtrArgs pa;
    for (int g = 0; g < 6; ++g) {
        pa.W[g] = (const float*)d_in[1 + 2 * g];
        pa.b[g] = (const float*)d_in[2 + 2 * g];
    }

    // Workspace layout:
    //   Y:    [1024][3072] fp32  = 12,582,912 B
    //   Aph:  [1024][1024] bf16  =  2,097,152 B
    //   Bph:  [3072][1024] bf16  =  6,291,456 B
    //   bias: [3072] fp32        =     12,288 B
    char* ws = (char*)d_ws;
    float*          Y    = (float*)ws;
    unsigned short* Aph  = (unsigned short*)(ws + 12582912);
    unsigned short* Bph  = (unsigned short*)(ws + 12582912 + 2097152);
    float*          bias = (float*)(ws + 12582912 + 2097152 + 6291456);

    convert_split<<<(XN + WN) / 256, 256, 0, stream>>>(x, pa, Aph, Bph, bias);

    dim3 g1(NCOLS / 128, M_ROWS / 64);   // 24 x 16 = 384 blocks
    gemm_mfma<<<g1, 256, 0, stream>>>(Aph, Bph, bias, Y);

    fused_attn<<<M_ROWS, 256, 0, stream>>>(Y, (float*)d_out);
}

// Round 6
// 107.954 us; speedup vs baseline: 1.8991x; 1.1207x over previous
//
#include <hip/hip_runtime.h>
#include <hip/hip_bf16.h>
#include <math.h>

// B=8, T=128, D=512. M = 1024 rows, N = 6*512 = 3072 concatenated outputs.
// Stage 0: split fp32 -> (hi,lo) bf16, packed per 32-K super-chunk.
// Stage 1: bf16 MFMA GEMM, C = Ah*Bh + Ah*Bl + Al*Bh.
// Stage 2: fused branches via degree-24 Taylor moment factorization.
//          R6: one wave per row, 8 j's/thread, moments accumulated in
//          registers (no cross-lane), reduced via LDS transpose —
//          replaces R5's 300 dependent shfl chains (latency-bound, ~30us).

#define M_ROWS 1024
#define DIMD   512
#define NCOLS  3072
#define KPHYS  1024

typedef __attribute__((ext_vector_type(8))) short short8;
typedef __attribute__((ext_vector_type(4))) float f32x4;

struct PtrArgs {
    const float* W[6];
    const float* b[6];
};

#define XN (M_ROWS * DIMD)
#define WN (NCOLS * DIMD)

__device__ __forceinline__ unsigned short bf16_rne(float v) {
    unsigned u = __float_as_uint(v);
    u = (u + 0x7FFFu + ((u >> 16) & 1u)) >> 16;
    return (unsigned short)u;
}

__device__ __constant__ float INVFACT[25] = {
    1.0f, 1.0f, 0.5f,
    1.6666666666666666e-01f, 4.1666666666666664e-02f, 8.3333333333333332e-03f,
    1.3888888888888889e-03f, 1.9841269841269841e-04f, 2.4801587301587302e-05f,
    2.7557319223985893e-06f, 2.7557319223985888e-07f, 2.5052108385441720e-08f,
    2.0876756987868100e-09f, 1.6059043836821613e-10f, 1.1470745597729725e-11f,
    7.6471637318198164e-13f, 4.7794773323873853e-14f, 2.8114572543455206e-15f,
    1.5619206968586225e-16f, 8.2206352466243295e-18f, 4.1103176233121648e-19f,
    1.9572941063391263e-20f, 8.8967913924505741e-22f, 3.8681701706306835e-23f,
    1.6117375710961184e-24f
};

// ---------------------------------------------------------------------------
// Stage 0: convert/split with interleaved hi/lo packing (unchanged).
// ---------------------------------------------------------------------------
__global__ __launch_bounds__(256) void convert_split(const float* __restrict__ x,
                                                     PtrArgs pa,
                                                     unsigned short* __restrict__ Aph,
                                                     unsigned short* __restrict__ Bph,
                                                     float* __restrict__ biasAll) {
    int idx = blockIdx.x * 256 + threadIdx.x;
    if (idx < NCOLS) {
        biasAll[idx] = pa.b[idx >> 9][idx & 511];
    }
    if (idx < XN) {
        int m = idx >> 9, k = idx & 511;
        int s = k >> 5, p = k & 31;
        float v = x[idx];
        unsigned short hb = bf16_rne(v);
        float hf = __uint_as_float(((unsigned)hb) << 16);
        unsigned short lb = bf16_rne(v - hf);
        Aph[(size_t)m * KPHYS + s * 64 + p]      = hb;
        Aph[(size_t)m * KPHYS + s * 64 + 32 + p] = lb;
    } else if (idx < XN + WN) {
        int j = idx - XN;
        int n = j >> 9, k = j & 511;
        int g = n >> 9, o = n & 511;
        int s = k >> 5, p = k & 31;
        float v = pa.W[g][(size_t)o * DIMD + k];
        unsigned short hb = bf16_rne(v);
        float hf = __uint_as_float(((unsigned)hb) << 16);
        unsigned short lb = bf16_rne(v - hf);
        Bph[(size_t)n * KPHYS + s * 64 + p]      = hb;
        Bph[(size_t)n * KPHYS + s * 64 + 32 + p] = lb;
    }
}

// ---------------------------------------------------------------------------
// Stage 1: MFMA GEMM (unchanged from R4/R5).
// ---------------------------------------------------------------------------
__global__ __launch_bounds__(256) void gemm_mfma(const unsigned short* __restrict__ A,
                                                 const unsigned short* __restrict__ B,
                                                 const float* __restrict__ biasAll,
                                                 float* __restrict__ Y) {
    __shared__ __align__(16) short As[64 * 128];
    __shared__ __align__(16) short Bs[128 * 128];

    const int tid  = threadIdx.x;
    const int m0   = blockIdx.y * 64;
    const int n0   = blockIdx.x * 128;
    const int lane = tid & 63;
    const int w    = tid >> 6;
    const int wm   = w & 1;
    const int wn   = w >> 1;
    const int l15  = lane & 15;
    const int quad = lane >> 4;

    f32x4 acc[2][4];
    #pragma unroll
    for (int i = 0; i < 2; ++i)
        #pragma unroll
        for (int j = 0; j < 4; ++j)
            acc[i][j] = (f32x4){0.f, 0.f, 0.f, 0.f};

    for (int it = 0; it < 8; ++it) {
        const int kbase = it * 128;
        __syncthreads();
        #pragma unroll
        for (int t = 0; t < 4; ++t) {
            int idx = t * 256 + tid;
            int r = idx >> 4, c = idx & 15;
            int cc = c ^ (r & 15);
            const unsigned short* ga = A + (size_t)(m0 + r) * KPHYS + kbase + cc * 8;
            __builtin_amdgcn_global_load_lds(
                (const __attribute__((address_space(1))) unsigned int*)ga,
                (__attribute__((address_space(3))) unsigned int*)&As[idx * 8], 16, 0, 0);
        }
        #pragma unroll
        for (int t = 0; t < 8; ++t) {
            int idx = t * 256 + tid;
            int r = idx >> 4, c = idx & 15;
            int cc = c ^ (r & 15);
            const unsigned short* gb = B + (size_t)(n0 + r) * KPHYS + kbase + cc * 8;
            __builtin_amdgcn_global_load_lds(
                (const __attribute__((address_space(1))) unsigned int*)gb,
                (__attribute__((address_space(3))) unsigned int*)&Bs[idx * 8], 16, 0, 0);
        }
        __syncthreads();

        #pragma unroll
        for (int kk = 0; kk < 2; ++kk) {
            short8 ah[2], al[2], bh[4], bl[4];
            #pragma unroll
            for (int mt = 0; mt < 2; ++mt) {
                int rA = wm * 32 + mt * 16 + l15;
                int ch = (kk * 8 + quad)     ^ (rA & 15);
                int cl = (kk * 8 + 4 + quad) ^ (rA & 15);
                ah[mt] = *(const short8*)&As[(rA * 16 + ch) * 8];
                al[mt] = *(const short8*)&As[(rA * 16 + cl) * 8];
            }
            #pragma unroll
            for (int nt = 0; nt < 4; ++nt) {
                int rB = wn * 64 + nt * 16 + l15;
                int ch = (kk * 8 + quad)     ^ (rB & 15);
                int cl = (kk * 8 + 4 + quad) ^ (rB & 15);
                bh[nt] = *(const short8*)&Bs[(rB * 16 + ch) * 8];
                bl[nt] = *(const short8*)&Bs[(rB * 16 + cl) * 8];
            }
            #pragma unroll
            for (int mt = 0; mt < 2; ++mt)
                #pragma unroll
                for (int nt = 0; nt < 4; ++nt) {
                    acc[mt][nt] = __builtin_amdgcn_mfma_f32_16x16x32_bf16(
                        ah[mt], bh[nt], acc[mt][nt], 0, 0, 0);
                    acc[mt][nt] = __builtin_amdgcn_mfma_f32_16x16x32_bf16(
                        ah[mt], bl[nt], acc[mt][nt], 0, 0, 0);
                    acc[mt][nt] = __builtin_amdgcn_mfma_f32_16x16x32_bf16(
                        al[mt], bh[nt], acc[mt][nt], 0, 0, 0);
                }
        }
    }

    #pragma unroll
    for (int nt = 0; nt < 4; ++nt) {
        int col = n0 + wn * 64 + nt * 16 + l15;
        float bv = biasAll[col];
        #pragma unroll
        for (int mt = 0; mt < 2; ++mt) {
            int row0 = m0 + wm * 32 + mt * 16 + quad * 4;
            #pragma unroll
            for (int r = 0; r < 4; ++r)
                Y[(size_t)(row0 + r) * NCOLS + col] = acc[mt][nt][r] + bv;
        }
    }
}

// ---------------------------------------------------------------------------
// Stage 2: fused branches. ONE wave per (b,t) row; lane owns 8 contiguous
// i's/j's (i0 = 8*lane). Moments in registers, reduced via LDS transpose:
//   write part[lane][p] (stride 53, odd -> 2-way banks = free),
//   lane p sums part[0..63][p] (lane-consecutive addrs = conflict-free).
// Horner: 16 independent fma chains (2 poly x 8 i).
// ---------------------------------------------------------------------------
#define PSTR 53   // part row stride (odd => conflict-free column access)

__global__ __launch_bounds__(64) void fused_attn(const float* __restrict__ Y,
                                                 float* __restrict__ out) {
    const int row = blockIdx.x;
    const int l   = threadIdx.x;        // 0..63
    const float* __restrict__ Yr = Y + (size_t)row * NCOLS;
    const int i0 = l * 8;

    __shared__ float part[64 * PSTR];
    __shared__ float cbuf[50];

    const float LOG2E = 1.4426950408889634f;

    float4 qf0 = *(const float4*)(Yr + i0);
    float4 qf1 = *(const float4*)(Yr + i0 + 4);
    float4 kf0 = *(const float4*)(Yr + 512 + i0);
    float4 kf1 = *(const float4*)(Yr + 512 + i0 + 4);
    float4 vf0 = *(const float4*)(Yr + 1024 + i0);
    float4 vf1 = *(const float4*)(Yr + 1024 + i0 + 4);
    float4 qt0 = *(const float4*)(Yr + 1536 + i0);
    float4 qt1 = *(const float4*)(Yr + 1536 + i0 + 4);
    float4 kt0 = *(const float4*)(Yr + 2048 + i0);
    float4 kt1 = *(const float4*)(Yr + 2048 + i0 + 4);
    float4 vt0 = *(const float4*)(Yr + 2560 + i0);
    float4 vt1 = *(const float4*)(Yr + 2560 + i0 + 4);

    // ---- feature branch: 8 exps + wave sum ----
    float e[8];
    e[0] = __builtin_amdgcn_exp2f(qf0.x * kf0.x * LOG2E);
    e[1] = __builtin_amdgcn_exp2f(qf0.y * kf0.y * LOG2E);
    e[2] = __builtin_amdgcn_exp2f(qf0.z * kf0.z * LOG2E);
    e[3] = __builtin_amdgcn_exp2f(qf0.w * kf0.w * LOG2E);
    e[4] = __builtin_amdgcn_exp2f(qf1.x * kf1.x * LOG2E);
    e[5] = __builtin_amdgcn_exp2f(qf1.y * kf1.y * LOG2E);
    e[6] = __builtin_amdgcn_exp2f(qf1.z * kf1.z * LOG2E);
    e[7] = __builtin_amdgcn_exp2f(qf1.w * kf1.w * LOG2E);
    float psum = ((e[0] + e[1]) + (e[2] + e[3])) + ((e[4] + e[5]) + (e[6] + e[7]));
    #pragma unroll
    for (int off = 32; off; off >>= 1) psum += __shfl_xor(psum, off);
    const float invS = 1.0f / psum;

    // ---- temporal moments, in-register over this lane's 8 j's ----
    float k[8] = {kt0.x, kt0.y, kt0.z, kt0.w, kt1.x, kt1.y, kt1.z, kt1.w};
    float v[8] = {vt0.x, vt0.y, vt0.z, vt0.w, vt1.x, vt1.y, vt1.z, vt1.w};
    float kp[8] = {1.f, 1.f, 1.f, 1.f, 1.f, 1.f, 1.f, 1.f};
    float* myrow = &part[l * PSTR];
    #pragma unroll
    for (int p = 0; p < 25; ++p) {
        float n = ((kp[0] + kp[1]) + (kp[2] + kp[3])) +
                  ((kp[4] + kp[5]) + (kp[6] + kp[7]));
        float m = fmaf(kp[7], v[7], fmaf(kp[6], v[6],
                  fmaf(kp[5], v[5], fmaf(kp[4], v[4],
                  fmaf(kp[3], v[3], fmaf(kp[2], v[2],
                  fmaf(kp[1], v[1], kp[0] * v[0])))))));
        myrow[p]      = m;
        myrow[25 + p] = n;
        #pragma unroll
        for (int j = 0; j < 8; ++j) kp[j] *= k[j];
    }
    __syncthreads();

    // ---- transpose-reduce: lane p sums column p over 64 rows ----
    if (l < 50) {
        float s = 0.f;
        #pragma unroll
        for (int i = 0; i < 64; ++i) s += part[i * PSTR + l];
        cbuf[l] = s * INVFACT[l < 25 ? l : l - 25];
    }
    __syncthreads();

    // ---- Horner for 8 i's (coeffs broadcast from LDS) ----
    float q[8] = {qt0.x, qt0.y, qt0.z, qt0.w, qt1.x, qt1.y, qt1.z, qt1.w};
    float F[8], G[8];
    {
        float cf = cbuf[24], cg = cbuf[49];
        #pragma unroll
        for (int c = 0; c < 8; ++c) { F[c] = cf; G[c] = cg; }
    }
    #pragma unroll
    for (int p = 23; p >= 0; --p) {
        float cf = cbuf[p], cg = cbuf[25 + p];
        #pragma unroll
        for (int c = 0; c < 8; ++c) {
            F[c] = fmaf(F[c], q[c], cf);
            G[c] = fmaf(G[c], q[c], cg);
        }
    }

    float4 o0, o1;
    o0.x = e[0] * invS * vf0.x + F[0] / G[0];
    o0.y = e[1] * invS * vf0.y + F[1] / G[1];
    o0.z = e[2] * invS * vf0.z + F[2] / G[2];
    o0.w = e[3] * invS * vf0.w + F[3] / G[3];
    o1.x = e[4] * invS * vf1.x + F[4] / G[4];
    o1.y = e[5] * invS * vf1.y + F[5] / G[5];
    o1.z = e[6] * invS * vf1.z + F[6] / G[6];
    o1.w = e[7] * invS * vf1.w + F[7] / G[7];
    *(float4*)(out + (size_t)row * DIMD + i0)     = o0;
    *(float4*)(out + (size_t)row * DIMD + i0 + 4) = o1;
}

extern "C" void kernel_launch(void* const* d_in, const int* in_sizes, int n_in,
                              void* d_out, int out_size, void* d_ws, size_t ws_size,
                              hipStream_t stream) {
    const float* x = (const float*)d_in[0];
    PtrArgs pa;
    for (int g = 0; g < 6; ++g) {
        pa.W[g] = (const float*)d_in[1 + 2 * g];
        pa.b[g] = (const float*)d_in[2 + 2 * g];
    }

    // Workspace layout:
    //   Y:    [1024][3072] fp32  = 12,582,912 B
    //   Aph:  [1024][1024] bf16  =  2,097,152 B
    //   Bph:  [3072][1024] bf16  =  6,291,456 B
    //   bias: [3072] fp32        =     12,288 B
    char* ws = (char*)d_ws;
    float*          Y    = (float*)ws;
    unsigned short* Aph  = (unsigned short*)(ws + 12582912);
    unsigned short* Bph  = (unsigned short*)(ws + 12582912 + 2097152);
    float*          bias = (float*)(ws + 12582912 + 2097152 + 6291456);

    convert_split<<<(XN + WN) / 256, 256, 0, stream>>>(x, pa, Aph, Bph, bias);

    dim3 g1(NCOLS / 128, M_ROWS / 64);   // 24 x 16 = 384 blocks
    gemm_mfma<<<g1, 256, 0, stream>>>(Aph, Bph, bias, Y);

    fused_attn<<<M_ROWS, 64, 0, stream>>>(Y, (float*)d_out);
}

// Round 7
// 105.102 us; speedup vs baseline: 1.9507x; 1.0271x over previous
//
#include <hip/hip_runtime.h>
#include <hip/hip_bf16.h>
#include <math.h>

// B=8, T=128, D=512. M = 1024 rows, N = 6*512 = 3072 concatenated outputs.
// Stage 0: split fp32 -> (hi,lo) bf16, packed per 32-K super-chunk
//          [32 hi | 32 lo]; float4-vectorized (4 elems/thread).
// Stage 1: bf16 MFMA GEMM, C = Ah*Bh + Ah*Bl + Al*Bh. R7: software-
//          pipelined LDS double-buffer — next stage's global_load_lds
//          issued after the barrier / before compute, so the compiler's
//          vmcnt(0)-before-s_barrier drains loads that flew during the
//          whole compute phase (fixes the 2-barrier drain stall at
//          1.5 blocks/CU). One 64-phys-short super-chunk per stage.
// Stage 2: fused branches via degree-24 Taylor moments (UNCHANGED from R6
//          for attribution).

#define M_ROWS 1024
#define DIMD   512
#define NCOLS  3072
#define KPHYS  1024

typedef __attribute__((ext_vector_type(8))) short short8;
typedef __attribute__((ext_vector_type(4))) float f32x4;
typedef __attribute__((ext_vector_type(4))) unsigned short u16x4;

struct PtrArgs {
    const float* W[6];
    const float* b[6];
};

#define XN (M_ROWS * DIMD)
#define WN (NCOLS * DIMD)

__device__ __forceinline__ unsigned short bf16_rne(float v) {
    unsigned u = __float_as_uint(v);
    u = (u + 0x7FFFu + ((u >> 16) & 1u)) >> 16;
    return (unsigned short)u;
}

__device__ __constant__ float INVFACT[25] = {
    1.0f, 1.0f, 0.5f,
    1.6666666666666666e-01f, 4.1666666666666664e-02f, 8.3333333333333332e-03f,
    1.3888888888888889e-03f, 1.9841269841269841e-04f, 2.4801587301587302e-05f,
    2.7557319223985893e-06f, 2.7557319223985888e-07f, 2.5052108385441720e-08f,
    2.0876756987868100e-09f, 1.6059043836821613e-10f, 1.1470745597729725e-11f,
    7.6471637318198164e-13f, 4.7794773323873853e-14f, 2.8114572543455206e-15f,
    1.5619206968586225e-16f, 8.2206352466243295e-18f, 4.1103176233121648e-19f,
    1.9572941063391263e-20f, 8.8967913924505741e-22f, 3.8681701706306835e-23f,
    1.6117375710961184e-24f
};

// ---------------------------------------------------------------------------
// Stage 0: convert/split, float4-vectorized. Thread handles 4 consecutive k
// (same 32-elem super-chunk): hi quad -> 8B store, lo quad -> 8B store.
// ---------------------------------------------------------------------------
__global__ __launch_bounds__(256) void convert_split(const float* __restrict__ x,
                                                     PtrArgs pa,
                                                     unsigned short* __restrict__ Aph,
                                                     unsigned short* __restrict__ Bph,
                                                     float* __restrict__ biasAll) {
    const int idx = blockIdx.x * 256 + threadIdx.x;   // vec4 index
    if (idx < NCOLS) {
        biasAll[idx] = pa.b[idx >> 9][idx & 511];
    }
    const int e4 = idx * 4;
    if (e4 < XN) {
        int m = e4 >> 9, k = e4 & 511;
        int s = k >> 5, p = k & 31;
        float4 v = *(const float4*)(x + e4);
        u16x4 hi, lo;
        hi.x = bf16_rne(v.x); lo.x = bf16_rne(v.x - __uint_as_float(((unsigned)hi.x) << 16));
        hi.y = bf16_rne(v.y); lo.y = bf16_rne(v.y - __uint_as_float(((unsigned)hi.y) << 16));
        hi.z = bf16_rne(v.z); lo.z = bf16_rne(v.z - __uint_as_float(((unsigned)hi.z) << 16));
        hi.w = bf16_rne(v.w); lo.w = bf16_rne(v.w - __uint_as_float(((unsigned)hi.w) << 16));
        *(u16x4*)&Aph[(size_t)m * KPHYS + s * 64 + p]      = hi;
        *(u16x4*)&Aph[(size_t)m * KPHYS + s * 64 + 32 + p] = lo;
    } else if (e4 < XN + WN) {
        int j = e4 - XN;
        int n = j >> 9, k = j & 511;
        int g = n >> 9, o = n & 511;
        int s = k >> 5, p = k & 31;
        float4 v = *(const float4*)(pa.W[g] + (size_t)o * DIMD + k);
        u16x4 hi, lo;
        hi.x = bf16_rne(v.x); lo.x = bf16_rne(v.x - __uint_as_float(((unsigned)hi.x) << 16));
        hi.y = bf16_rne(v.y); lo.y = bf16_rne(v.y - __uint_as_float(((unsigned)hi.y) << 16));
        hi.z = bf16_rne(v.z); lo.z = bf16_rne(v.z - __uint_as_float(((unsigned)hi.z) << 16));
        hi.w = bf16_rne(v.w); lo.w = bf16_rne(v.w - __uint_as_float(((unsigned)hi.w) << 16));
        *(u16x4*)&Bph[(size_t)n * KPHYS + s * 64 + p]      = hi;
        *(u16x4*)&Bph[(size_t)n * KPHYS + s * 64 + 32 + p] = lo;
    }
}

// ---------------------------------------------------------------------------
// Stage 1: software-pipelined MFMA GEMM. Block tile 64(M) x 128(N); 4 waves
// as 2x2, wave tile 32x64 = 2x4 of 16x16x32 MFMAs x3 hi/lo terms.
// One stage = one 32-logical-K super-chunk (64 phys shorts/row): As 8 KB,
// Bs 16 KB per buffer; dbuf total 48 KB. 16 stages.
// Pipeline per iter: barrier (drains stage-it loads) -> issue stage-(it+1)
// loads into other buffer -> compute stage it. The next barrier's vmcnt(0)
// lands after a full compute phase of overlap.
// Chunk index XOR-swizzled with (row&7) on the GLOBAL address.
// ---------------------------------------------------------------------------
__global__ __launch_bounds__(256) void gemm_mfma(const unsigned short* __restrict__ A,
                                                 const unsigned short* __restrict__ B,
                                                 const float* __restrict__ biasAll,
                                                 float* __restrict__ Y) {
    __shared__ __align__(16) short As[2][64 * 64];    // 8 KB each
    __shared__ __align__(16) short Bs[2][128 * 64];   // 16 KB each

    const int tid  = threadIdx.x;
    const int m0   = blockIdx.y * 64;
    const int n0   = blockIdx.x * 128;
    const int lane = tid & 63;
    const int w    = tid >> 6;
    const int wm   = w & 1;
    const int wn   = w >> 1;
    const int l15  = lane & 15;
    const int quad = lane >> 4;

    f32x4 acc[2][4];
    #pragma unroll
    for (int i = 0; i < 2; ++i)
        #pragma unroll
        for (int j = 0; j < 4; ++j)
            acc[i][j] = (f32x4){0.f, 0.f, 0.f, 0.f};

    auto stage = [&](int it, int buf) {
        const int kbase = it * 64;
        #pragma unroll
        for (int t = 0; t < 2; ++t) {        // A: 64 rows x 8 chunks
            int idx = t * 256 + tid;
            int r = idx >> 3, c = idx & 7;
            int cc = c ^ (r & 7);
            const unsigned short* ga = A + (size_t)(m0 + r) * KPHYS + kbase + cc * 8;
            __builtin_amdgcn_global_load_lds(
                (const __attribute__((address_space(1))) unsigned int*)ga,
                (__attribute__((address_space(3))) unsigned int*)&As[buf][idx * 8], 16, 0, 0);
        }
        #pragma unroll
        for (int t = 0; t < 4; ++t) {        // B: 128 rows x 8 chunks
            int idx = t * 256 + tid;
            int r = idx >> 3, c = idx & 7;
            int cc = c ^ (r & 7);
            const unsigned short* gb = B + (size_t)(n0 + r) * KPHYS + kbase + cc * 8;
            __builtin_amdgcn_global_load_lds(
                (const __attribute__((address_space(1))) unsigned int*)gb,
                (__attribute__((address_space(3))) unsigned int*)&Bs[buf][idx * 8], 16, 0, 0);
        }
    };

    stage(0, 0);

    for (int it = 0; it < 16; ++it) {
        __syncthreads();                       // vmcnt(0) drain of stage-it loads
        if (it + 1 < 16) stage(it + 1, (it + 1) & 1);   // fly during compute

        const short* as = As[it & 1];
        const short* bs = Bs[it & 1];
        short8 ah[2], al[2], bh[4], bl[4];
        #pragma unroll
        for (int mt = 0; mt < 2; ++mt) {
            int rA = wm * 32 + mt * 16 + l15;
            int ch = quad ^ (rA & 7);
            int cl = (4 + quad) ^ (rA & 7);
            ah[mt] = *(const short8*)&as[(rA * 8 + ch) * 8];
            al[mt] = *(const short8*)&as[(rA * 8 + cl) * 8];
        }
        #pragma unroll
        for (int nt = 0; nt < 4; ++nt) {
            int rB = wn * 64 + nt * 16 + l15;
            int ch = quad ^ (rB & 7);
            int cl = (4 + quad) ^ (rB & 7);
            bh[nt] = *(const short8*)&bs[(rB * 8 + ch) * 8];
            bl[nt] = *(const short8*)&bs[(rB * 8 + cl) * 8];
        }
        #pragma unroll
        for (int mt = 0; mt < 2; ++mt)
            #pragma unroll
            for (int nt = 0; nt < 4; ++nt) {
                acc[mt][nt] = __builtin_amdgcn_mfma_f32_16x16x32_bf16(
                    ah[mt], bh[nt], acc[mt][nt], 0, 0, 0);
                acc[mt][nt] = __builtin_amdgcn_mfma_f32_16x16x32_bf16(
                    ah[mt], bl[nt], acc[mt][nt], 0, 0, 0);
                acc[mt][nt] = __builtin_amdgcn_mfma_f32_16x16x32_bf16(
                    al[mt], bh[nt], acc[mt][nt], 0, 0, 0);
            }
    }

    // Epilogue. C/D: col = lane&15, row = quad*4 + reg  [m89-verified]
    #pragma unroll
    for (int nt = 0; nt < 4; ++nt) {
        int col = n0 + wn * 64 + nt * 16 + l15;
        float bv = biasAll[col];
        #pragma unroll
        for (int mt = 0; mt < 2; ++mt) {
            int row0 = m0 + wm * 32 + mt * 16 + quad * 4;
            #pragma unroll
            for (int r = 0; r < 4; ++r)
                Y[(size_t)(row0 + r) * NCOLS + col] = acc[mt][nt][r] + bv;
        }
    }
}

// ---------------------------------------------------------------------------
// Stage 2: fused branches (UNCHANGED from R6). One wave per row; moments in
// registers, LDS-transpose reduce, Horner per i.
// ---------------------------------------------------------------------------
#define PSTR 53

__global__ __launch_bounds__(64) void fused_attn(const float* __restrict__ Y,
                                                 float* __restrict__ out) {
    const int row = blockIdx.x;
    const int l   = threadIdx.x;
    const float* __restrict__ Yr = Y + (size_t)row * NCOLS;
    const int i0 = l * 8;

    __shared__ float part[64 * PSTR];
    __shared__ float cbuf[50];

    const float LOG2E = 1.4426950408889634f;

    float4 qf0 = *(const float4*)(Yr + i0);
    float4 qf1 = *(const float4*)(Yr + i0 + 4);
    float4 kf0 = *(const float4*)(Yr + 512 + i0);
    float4 kf1 = *(const float4*)(Yr + 512 + i0 + 4);
    float4 vf0 = *(const float4*)(Yr + 1024 + i0);
    float4 vf1 = *(const float4*)(Yr + 1024 + i0 + 4);
    float4 qt0 = *(const float4*)(Yr + 1536 + i0);
    float4 qt1 = *(const float4*)(Yr + 1536 + i0 + 4);
    float4 kt0 = *(const float4*)(Yr + 2048 + i0);
    float4 kt1 = *(const float4*)(Yr + 2048 + i0 + 4);
    float4 vt0 = *(const float4*)(Yr + 2560 + i0);
    float4 vt1 = *(const float4*)(Yr + 2560 + i0 + 4);

    float e[8];
    e[0] = __builtin_amdgcn_exp2f(qf0.x * kf0.x * LOG2E);
    e[1] = __builtin_amdgcn_exp2f(qf0.y * kf0.y * LOG2E);
    e[2] = __builtin_amdgcn_exp2f(qf0.z * kf0.z * LOG2E);
    e[3] = __builtin_amdgcn_exp2f(qf0.w * kf0.w * LOG2E);
    e[4] = __builtin_amdgcn_exp2f(qf1.x * kf1.x * LOG2E);
    e[5] = __builtin_amdgcn_exp2f(qf1.y * kf1.y * LOG2E);
    e[6] = __builtin_amdgcn_exp2f(qf1.z * kf1.z * LOG2E);
    e[7] = __builtin_amdgcn_exp2f(qf1.w * kf1.w * LOG2E);
    float psum = ((e[0] + e[1]) + (e[2] + e[3])) + ((e[4] + e[5]) + (e[6] + e[7]));
    #pragma unroll
    for (int off = 32; off; off >>= 1) psum += __shfl_xor(psum, off);
    const float invS = 1.0f / psum;

    float k[8] = {kt0.x, kt0.y, kt0.z, kt0.w, kt1.x, kt1.y, kt1.z, kt1.w};
    float v[8] = {vt0.x, vt0.y, vt0.z, vt0.w, vt1.x, vt1.y, vt1.z, vt1.w};
    float kp[8] = {1.f, 1.f, 1.f, 1.f, 1.f, 1.f, 1.f, 1.f};
    float* myrow = &part[l * PSTR];
    #pragma unroll
    for (int p = 0; p < 25; ++p) {
        float n = ((kp[0] + kp[1]) + (kp[2] + kp[3])) +
                  ((kp[4] + kp[5]) + (kp[6] + kp[7]));
        float m = fmaf(kp[7], v[7], fmaf(kp[6], v[6],
                  fmaf(kp[5], v[5], fmaf(kp[4], v[4],
                  fmaf(kp[3], v[3], fmaf(kp[2], v[2],
                  fmaf(kp[1], v[1], kp[0] * v[0])))))));
        myrow[p]      = m;
        myrow[25 + p] = n;
        #pragma unroll
        for (int j = 0; j < 8; ++j) kp[j] *= k[j];
    }
    __syncthreads();

    if (l < 50) {
        float s = 0.f;
        #pragma unroll
        for (int i = 0; i < 64; ++i) s += part[i * PSTR + l];
        cbuf[l] = s * INVFACT[l < 25 ? l : l - 25];
    }
    __syncthreads();

    float q[8] = {qt0.x, qt0.y, qt0.z, qt0.w, qt1.x, qt1.y, qt1.z, qt1.w};
    float F[8], G[8];
    {
        float cf = cbuf[24], cg = cbuf[49];
        #pragma unroll
        for (int c = 0; c < 8; ++c) { F[c] = cf; G[c] = cg; }
    }
    #pragma unroll
    for (int p = 23; p >= 0; --p) {
        float cf = cbuf[p], cg = cbuf[25 + p];
        #pragma unroll
        for (int c = 0; c < 8; ++c) {
            F[c] = fmaf(F[c], q[c], cf);
            G[c] = fmaf(G[c], q[c], cg);
        }
    }

    float4 o0, o1;
    o0.x = e[0] * invS * vf0.x + F[0] / G[0];
    o0.y = e[1] * invS * vf0.y + F[1] / G[1];
    o0.z = e[2] * invS * vf0.z + F[2] / G[2];
    o0.w = e[3] * invS * vf0.w + F[3] / G[3];
    o1.x = e[4] * invS * vf1.x + F[4] / G[4];
    o1.y = e[5] * invS * vf1.y + F[5] / G[5];
    o1.z = e[6] * invS * vf1.z + F[6] / G[6];
    o1.w = e[7] * invS * vf1.w + F[7] / G[7];
    *(float4*)(out + (size_t)row * DIMD + i0)     = o0;
    *(float4*)(out + (size_t)row * DIMD + i0 + 4) = o1;
}

extern "C" void kernel_launch(void* const* d_in, const int* in_sizes, int n_in,
                              void* d_out, int out_size, void* d_ws, size_t ws_size,
                              hipStream_t stream) {
    const float* x = (const float*)d_in[0];
    PtrArgs pa;
    for (int g = 0; g < 6; ++g) {
        pa.W[g] = (const float*)d_in[1 + 2 * g];
        pa.b[g] = (const float*)d_in[2 + 2 * g];
    }

    // Workspace layout:
    //   Y:    [1024][3072] fp32  = 12,582,912 B
    //   Aph:  [1024][1024] bf16  =  2,097,152 B
    //   Bph:  [3072][1024] bf16  =  6,291,456 B
    //   bias: [3072] fp32        =     12,288 B
    char* ws = (char*)d_ws;
    float*          Y    = (float*)ws;
    unsigned short* Aph  = (unsigned short*)(ws + 12582912);
    unsigned short* Bph  = (unsigned short*)(ws + 12582912 + 2097152);
    float*          bias = (float*)(ws + 12582912 + 2097152 + 6291456);

    convert_split<<<(XN + WN) / 4 / 256, 256, 0, stream>>>(x, pa, Aph, Bph, bias);

    dim3 g1(NCOLS / 128, M_ROWS / 64);   // 24 x 16 = 384 blocks
    gemm_mfma<<<g1, 256, 0, stream>>>(Aph, Bph, bias, Y);

    fused_attn<<<M_ROWS, 64, 0, stream>>>(Y, (float*)d_out);
}